// Round 1
// 519.380 us; speedup vs baseline: 1.0868x; 1.0868x over previous
//
#include <hip/hip_runtime.h>
#include <cstdint>

typedef __bf16 bf16_t;
typedef bf16_t bf16x8 __attribute__((ext_vector_type(8)));
typedef bf16_t bf16x4 __attribute__((ext_vector_type(4)));
typedef float  floatx4 __attribute__((ext_vector_type(4)));

#define S_ALL 2304
#define SIMG  2048
#define NH    24
#define HD    128
#define DIM   3072
#define NQKV  9216

// exp(s-12) computed as exp2(s*log2e - 12*log2e); log2e folded into q pre-scale
#define SHIFT2 17.312340490667562f
#define QSCALE 0.12751744f   /* (1/sqrt(128)) * log2(e) */

typedef __attribute__((address_space(1))) void* gp1_t;
typedef __attribute__((address_space(3))) void* lp3_t;

__device__ __forceinline__ void async16(const void* g, void* l) {
    __builtin_amdgcn_global_load_lds((gp1_t)(g), (lp3_t)(l), 16, 0, 0);
}
__device__ __forceinline__ floatx4 mfma_bf16(bf16x8 a, bf16x8 b, floatx4 c) {
    return __builtin_amdgcn_mfma_f32_16x16x32_bf16(a, b, c, 0, 0, 0);
}
// raw barrier: no vmcnt/lgkmcnt drain (unlike __syncthreads), with compiler mem fence
__device__ __forceinline__ void barrier_raw() {
    asm volatile("s_barrier" ::: "memory");
}

// ---------------- x concat + fp32->bf16 ----------------
__global__ __launch_bounds__(256) void k_convert_x(const float* __restrict__ hid,
                                                   const float* __restrict__ enc,
                                                   bf16_t* __restrict__ xb) {
    long i = ((long)blockIdx.x * 256 + threadIdx.x) * 4;
    const long HN = (long)SIMG * DIM;
    float4 f = (i < HN) ? *(const float4*)(hid + i) : *(const float4*)(enc + (i - HN));
    bf16x4 o;
    o[0] = (bf16_t)f.x; o[1] = (bf16_t)f.y; o[2] = (bf16_t)f.z; o[3] = (bf16_t)f.w;
    *(bf16x4*)(xb + i) = o;
}

// ---------------- weight transpose-convert: 4 weights in one launch (blockIdx.z) ----------------
__global__ __launch_bounds__(256) void k_wT4(const float* __restrict__ wq, const float* __restrict__ wk,
                                             const float* __restrict__ wv, const float* __restrict__ wo,
                                             bf16_t* __restrict__ wTq, bf16_t* __restrict__ woT) {
    __shared__ __align__(16) bf16_t T[64][72];
    int z = blockIdx.z;
    const float* W = (z == 0) ? wq : (z == 1) ? wk : (z == 2) ? wv : wo;
    bf16_t* Wt = (z < 3) ? (wTq + (long)z * DIM * DIM) : woT;
    int r0 = blockIdx.x * 64, c0 = blockIdx.y * 64;
    int tid = threadIdx.x;
    int lr = tid >> 2, lc = (tid & 3) * 16;
    const float* src = W + (long)(r0 + lr) * DIM + c0 + lc;
#pragma unroll
    for (int i = 0; i < 16; i += 4) {
        float4 f = *(const float4*)(src + i);
        T[lr][lc + i + 0] = (bf16_t)f.x;
        T[lr][lc + i + 1] = (bf16_t)f.y;
        T[lr][lc + i + 2] = (bf16_t)f.z;
        T[lr][lc + i + 3] = (bf16_t)f.w;
    }
    __syncthreads();
    bf16x8 a, b;
#pragma unroll
    for (int i = 0; i < 8; i++) a[i] = T[lc + i][lr];
#pragma unroll
    for (int i = 0; i < 8; i++) b[i] = T[lc + 8 + i][lr];
    bf16_t* dst = Wt + (long)(c0 + lr) * DIM + r0 + lc;
    *(bf16x8*)dst = a;
    *(bf16x8*)(dst + 8) = b;
}

// ---------------- pipelined GEMM mainloop: 256x128 tile, BK=64, 8 waves (4M x 2N) ----------------
// LDS: 3 x A-buf(32KB) at 0, 3 x B-buf(16KB) at 98304. 3-deep rotation:
//   iter kt computes from buf[kt%3] and issues stage of tile kt+2 into buf[(kt+2)%3],
//   which was last read in iter kt-1 (behind a barrier) -> race-free by construction.
// Counted vmcnt(6) at tile boundary keeps tile kt+2's 6 loads/wave in flight (T4);
// 2 phases/tile of {ds_read || stage-issue -> s_barrier -> setprio+16 MFMA} (T3+T5).
// LDS swizzle: LDS[row][chunk c] holds global k-chunk (c ^ (row&7)) via pre-swizzled source (T2).
__device__ __forceinline__ void gemm_pipe_256x128(const bf16_t* __restrict__ A,
                                                  const bf16_t* __restrict__ Bt,
                                                  long m0, long n0, const int K,
                                                  char* smem, int tid,
                                                  floatx4 acc[4][4]) {
    const int wave = tid >> 6, lane = tid & 63;
    const int quad = lane >> 4, l16 = lane & 15;
    const int wm = (wave >> 1) * 64;
    const int wn = (wave & 1) * 64;
    const int kxor = ((lane & 7) ^ ((lane >> 3) & 7)) * 8;
    const bf16_t* Ag = A + (m0 + wave * 32 + (lane >> 3)) * K + kxor;
    const bf16_t* Bg = Bt + (n0 + wave * 16 + (lane >> 3)) * K + kxor;
    char* Asl = smem + wave * 4096;           // + buf*32768 + c2*1024 (+ lane*16 by HW)
    char* Bsl = smem + 98304 + wave * 2048;   // + buf*16384 + c2*1024

    const int NT = K >> 6;  // 48

    // prologue: stage tiles 0 and 1
#pragma unroll
    for (int c2 = 0; c2 < 4; ++c2) async16(Ag + (long)c2 * 8 * K,      Asl + c2 * 1024);
#pragma unroll
    for (int c2 = 0; c2 < 2; ++c2) async16(Bg + (long)c2 * 8 * K,      Bsl + c2 * 1024);
#pragma unroll
    for (int c2 = 0; c2 < 4; ++c2) async16(Ag + (long)c2 * 8 * K + 64, Asl + 32768 + c2 * 1024);
#pragma unroll
    for (int c2 = 0; c2 < 2; ++c2) async16(Bg + (long)c2 * 8 * K + 64, Bsl + 16384 + c2 * 1024);
    asm volatile("s_waitcnt vmcnt(6)" ::: "memory");  // tile 0 landed; tile 1 in flight
    barrier_raw();

    int cur = 0;
    for (int kt = 0; kt < NT; ++kt) {
        const bf16_t* As = (const bf16_t*)(smem + cur * 32768);
        const bf16_t* Bs = (const bf16_t*)(smem + 98304 + cur * 16384);
        int nxt = cur + 2; if (nxt >= 3) nxt -= 3;
        char* Asd = Asl + nxt * 32768;
        char* Bsd = Bsl + nxt * 16384;
        const long kg = (long)(kt + 2) * 64;
        const bool issue = (kt < NT - 2);

        bf16x8 af[4], bfr[4];
        // ---- phase 0 : ks = 0 ----
        {
            int ch = (quad ^ (l16 & 7)) * 8;
#pragma unroll
            for (int i = 0; i < 4; i++) af[i]  = *(const bf16x8*)&As[(wm + i * 16 + l16) * 64 + ch];
#pragma unroll
            for (int j = 0; j < 4; j++) bfr[j] = *(const bf16x8*)&Bs[(wn + j * 16 + l16) * 64 + ch];
        }
        if (issue) {
            async16(Ag + kg,          Asd);
            async16(Ag + 8 * K + kg,  Asd + 1024);
            async16(Bg + kg,          Bsd);
        }
        barrier_raw();
        __builtin_amdgcn_s_setprio(1);
#pragma unroll
        for (int i = 0; i < 4; i++)
#pragma unroll
            for (int j = 0; j < 4; j++) acc[i][j] = mfma_bf16(af[i], bfr[j], acc[i][j]);
        __builtin_amdgcn_s_setprio(0);

        // ---- phase 1 : ks = 1 ----
        {
            int ch = ((4 + quad) ^ (l16 & 7)) * 8;
#pragma unroll
            for (int i = 0; i < 4; i++) af[i]  = *(const bf16x8*)&As[(wm + i * 16 + l16) * 64 + ch];
#pragma unroll
            for (int j = 0; j < 4; j++) bfr[j] = *(const bf16x8*)&Bs[(wn + j * 16 + l16) * 64 + ch];
        }
        if (issue) {
            async16(Ag + 16 * K + kg, Asd + 2048);
            async16(Ag + 24 * K + kg, Asd + 3072);
            async16(Bg + 8 * K + kg,  Bsd + 1024);
        }
        barrier_raw();
        __builtin_amdgcn_s_setprio(1);
#pragma unroll
        for (int i = 0; i < 4; i++)
#pragma unroll
            for (int j = 0; j < 4; j++) acc[i][j] = mfma_bf16(af[i], bfr[j], acc[i][j]);
        __builtin_amdgcn_s_setprio(0);

        // ---- tile boundary: ensure tile kt+1 landed; keep kt+2's 6 loads in flight ----
        if (issue) asm volatile("s_waitcnt vmcnt(6)" ::: "memory");
        else       asm volatile("s_waitcnt vmcnt(0)" ::: "memory");  // epilogue of pipeline only
        barrier_raw();
        cur += 1; if (cur >= 3) cur -= 3;
    }
}

// ---------------- fused QKV GEMM + bias + RMSNorm + RoPE + V-transpose ----------------
// C[M=2304, N=9216] = x[2304,3072] * Wt[9216,3072]^T. Each 128-col tile is one (t,h);
// 256-row blocks (M = 9*256 exactly; rope boundary at 2048 = 8*256 stays block-uniform).
__global__ __launch_bounds__(512, 2) void k_gemm_qkv(const bf16_t* __restrict__ A,
                                                     const bf16_t* __restrict__ Bt,
                                                     const float* __restrict__ bq_,
                                                     const float* __restrict__ bk_,
                                                     const float* __restrict__ bv_,
                                                     const float* __restrict__ rope_cos,
                                                     const float* __restrict__ rope_sin,
                                                     const float* __restrict__ nqw,
                                                     const float* __restrict__ nkw,
                                                     bf16_t* __restrict__ qo,
                                                     bf16_t* __restrict__ ko,
                                                     bf16_t* __restrict__ vT) {
    __shared__ __align__(16) char smem[147456];  // 144 KB: 3x(32K A) + 3x(16K B)
    int tid = threadIdx.x;
    int wave = tid >> 6, lane = tid & 63;
    int quad = lane >> 4, l16 = lane & 15;
    long m0 = (long)blockIdx.y * 256, n0 = (long)blockIdx.x * 128;
    int t = blockIdx.x / 24, h = blockIdx.x % 24;
    int wm = (wave >> 1) * 64, wn = (wave & 1) * 64;

    floatx4 zero = {0.f, 0.f, 0.f, 0.f};
    floatx4 acc[4][4];
#pragma unroll
    for (int i = 0; i < 4; i++)
#pragma unroll
        for (int j = 0; j < 4; j++) acc[i][j] = zero;

    gemm_pipe_256x128(A, Bt, m0, n0, DIM, smem, tid, acc);
    // mainloop ends with barrier_raw(): all LDS reads complete -> smem reusable

    int dcol[4];
#pragma unroll
    for (int j = 0; j < 4; j++) dcol[j] = wn + j * 16 + l16;

    if (t == 2) {
        // ---- V: bias add + LDS transpose -> vT[h][d][s], two 128-row halves ----
        float bias4[4];
#pragma unroll
        for (int j = 0; j < 4; j++) bias4[j] = bv_[h * HD + dcol[j]];
        char* vbuf = smem;  // 32 KB scratch
        int wmi = wave >> 1;
#pragma unroll
        for (int half = 0; half < 2; ++half) {
            if ((wmi >> 1) == half) {
#pragma unroll
                for (int i = 0; i < 4; i++)
#pragma unroll
                    for (int r = 0; r < 4; r++) {
                        int s_l = wm - half * 128 + i * 16 + quad * 4 + r;  // 0..127
#pragma unroll
                        for (int j = 0; j < 4; j++) {
                            int d = dcol[j];
                            int chunk = d * 16 + ((s_l >> 3) ^ (d & 15));
                            *(bf16_t*)(vbuf + chunk * 16 + (s_l & 7) * 2) = (bf16_t)(acc[i][j][r] + bias4[j]);
                        }
                    }
            }
            __syncthreads();
            int d = tid >> 2, sh = tid & 3;
            bf16_t* dstv = vT + (long)h * HD * S_ALL + (long)d * S_ALL + m0 + half * 128 + sh * 32;
#pragma unroll
            for (int k8 = 0; k8 < 4; ++k8) {
                int s8 = sh * 4 + k8;
                bf16x8 frag = *(const bf16x8*)(vbuf + (d * 16 + (s8 ^ (d & 15))) * 16);
                *(bf16x8*)(dstv + k8 * 8) = frag;
            }
            __syncthreads();
        }
    } else {
        // ---- Q/K: bias + RMSNorm + RoPE (+QSCALE for q), write [h][s][d] ----
        float* ssq = (float*)smem;  // [256][2]
        const float* bp = t ? bk_ : bq_;
        const float* nw = t ? nkw : nqw;
        float bias4[4], wv4[4];
#pragma unroll
        for (int j = 0; j < 4; j++) {
            bias4[j] = bp[h * HD + dcol[j]];
            wv4[j] = nw[dcol[j]];
        }
        int wnh = wave & 1;
#pragma unroll
        for (int i = 0; i < 4; i++)
#pragma unroll
            for (int r = 0; r < 4; r++) {
                int row = wm + i * 16 + quad * 4 + r;
                float s2 = 0.f;
#pragma unroll
                for (int j = 0; j < 4; j++) {
                    float v = acc[i][j][r] + bias4[j];
                    acc[i][j][r] = v;
                    s2 += v * v;
                }
                s2 += __shfl_xor(s2, 1);
                s2 += __shfl_xor(s2, 2);
                s2 += __shfl_xor(s2, 4);
                s2 += __shfl_xor(s2, 8);
                if (l16 == 0) ssq[row * 2 + wnh] = s2;
            }
        __syncthreads();
        bf16_t* dst = (t ? ko : qo) + (long)h * S_ALL * HD;
        bool do_rope = (m0 < SIMG);  // block-uniform: 256-row tiles align to the 2048 boundary
#pragma unroll
        for (int i = 0; i < 4; i++)
#pragma unroll
            for (int r = 0; r < 4; r++) {
                int row = wm + i * 16 + quad * 4 + r;
                int s_abs = (int)m0 + row;
                float tot = ssq[row * 2] + ssq[row * 2 + 1];
                float rms = rsqrtf(tot * (1.0f / 128.0f) + 1e-6f);
                float y[4];
#pragma unroll
                for (int j = 0; j < 4; j++) y[j] = acc[i][j][r] * rms * wv4[j];
                if (do_rope) {
                    const float* cp = rope_cos + (long)s_abs * HD;
                    const float* sp = rope_sin + (long)s_abs * HD;
#pragma unroll
                    for (int j = 0; j < 4; j++) {
                        float c = cp[dcol[j]], sn = sp[dcol[j]];
                        float px = __shfl_xor(y[j], 1);
                        y[j] = y[j] * c + ((l16 & 1) ? px : -px) * sn;
                    }
                }
#pragma unroll
                for (int j = 0; j < 4; j++) {
                    float v = t ? y[j] : y[j] * QSCALE;
                    dst[(long)s_abs * HD + dcol[j]] = (bf16_t)v;
                }
            }
    }
}

// ---------------- GEMM: C[M,N] = A[M,K] * Bt[N,K]^T + bias (O-proj) ----------------
__global__ __launch_bounds__(512, 2) void k_gemm_bt(const bf16_t* __restrict__ A,
                                                    const bf16_t* __restrict__ Bt,
                                                    const float* __restrict__ bias,
                                                    bf16_t* __restrict__ Cb, float* __restrict__ Cf,
                                                    int M, int N, int K) {
    __shared__ __align__(16) char smem[147456];
    int tid = threadIdx.x;
    int wave = tid >> 6, lane = tid & 63;
    int quad = lane >> 4, l16 = lane & 15;
    long m0 = (long)blockIdx.y * 256, n0 = (long)blockIdx.x * 128;
    int wm = (wave >> 1) * 64, wn = (wave & 1) * 64;

    floatx4 zero = {0.f, 0.f, 0.f, 0.f};
    floatx4 acc[4][4];
#pragma unroll
    for (int i = 0; i < 4; i++)
#pragma unroll
        for (int j = 0; j < 4; j++) acc[i][j] = zero;

    gemm_pipe_256x128(A, Bt, m0, n0, K, smem, tid, acc);

#pragma unroll
    for (int i = 0; i < 4; i++) {
        long rowb = m0 + wm + i * 16 + quad * 4;
#pragma unroll
        for (int j = 0; j < 4; j++) {
            long col = n0 + wn + j * 16 + l16;
            float bv = bias ? bias[col] : 0.0f;
#pragma unroll
            for (int r = 0; r < 4; r++) {
                float v = acc[i][j][r] + bv;
                long idx = (rowb + r) * N + col;
                if (Cb) Cb[idx] = (bf16_t)v;
                else    Cf[idx] = v;
            }
        }
    }
}

// ---------------- flash attention: swizzled LDS, fixed-shift softmax ----------------
// grid (18, 24): 128 q-rows/block, 4 waves x 32 q-rows (2 subtiles of 16); K-blocks of 64.
__global__ __launch_bounds__(256, 2) void k_attn(const bf16_t* __restrict__ q,
                                                 const bf16_t* __restrict__ k,
                                                 const bf16_t* __restrict__ vT,
                                                 bf16_t* __restrict__ ao,
                                                 float* __restrict__ out_txt) {
    __shared__ __align__(16) bf16_t Ks[64 * 128];       // 16 KB
    __shared__ __align__(16) bf16_t VTs[128 * 64];      // 16 KB
    __shared__ __align__(16) bf16_t Ps[4][2][16 * 64];  // 16 KB (per wave, per subtile)
    int tid = threadIdx.x, wave = tid >> 6, lane = tid & 63;
    int quad = lane >> 4, l16 = lane & 15;
    int h = blockIdx.y;
    int q0 = blockIdx.x * 128 + wave * 32;
    const long hbase = (long)h * S_ALL * HD;
    const char* kgb = (const char*)(k + hbase);
    const char* vgb = (const char*)(vT + hbase);

    int koffB[4], voffB[4], slotB[4];
#pragma unroll
    for (int c2 = 0; c2 < 4; ++c2) {
        int L = (wave * 4 + c2) * 64 + lane;
        slotB[c2] = L;
        int rk = L >> 4, ck = (L & 15) ^ (rk & 15);
        koffB[c2] = rk * 256 + ck * 16;
        int rv = L >> 3, cv = (L & 7) ^ (rv & 7) ^ (((rv >> 3) & 1) << 2);
        voffB[c2] = rv * (S_ALL * 2) + cv * 16;
    }

    bf16x8 qf[2][4];
#pragma unroll
    for (int st = 0; st < 2; ++st) {
        const bf16_t* qp = q + hbase + (long)(q0 + st * 16 + l16) * HD + quad * 8;
#pragma unroll
        for (int ks = 0; ks < 4; ++ks) qf[st][ks] = *(const bf16x8*)(qp + ks * 32);
    }

    floatx4 zero = {0.f, 0.f, 0.f, 0.f};
    floatx4 o0[8], o1[8];
#pragma unroll
    for (int ni = 0; ni < 8; ++ni) { o0[ni] = zero; o1[ni] = zero; }
    floatx4 lac0 = zero, lac1 = zero;

    for (int kb = 0; kb < S_ALL / 64; ++kb) {
        const char* kg = kgb + (long)kb * 16384;
        const char* vg = vgb + kb * 128;
#pragma unroll
        for (int c2 = 0; c2 < 4; ++c2) {
            async16(kg + koffB[c2], (char*)Ks + slotB[c2] * 16);
            async16(vg + voffB[c2], (char*)VTs + slotB[c2] * 16);
        }
        __syncthreads();

        floatx4 s0[4], s1[4];
#pragma unroll
        for (int ni = 0; ni < 4; ++ni) { s0[ni] = zero; s1[ni] = zero; }
#pragma unroll
        for (int ks = 0; ks < 4; ++ks)
#pragma unroll
            for (int ni = 0; ni < 4; ++ni) {
                int slot = (ni * 16 + l16) * 16 + ((ks * 4 + quad) ^ l16);
                bf16x8 kf = *(const bf16x8*)&Ks[slot * 8];
                s0[ni] = mfma_bf16(qf[0][ks], kf, s0[ni]);
                s1[ni] = mfma_bf16(qf[1][ks], kf, s1[ni]);
            }

#pragma unroll
        for (int st = 0; st < 2; ++st) {
#pragma unroll
            for (int ni = 0; ni < 4; ++ni) {
                floatx4 sv = st ? s1[ni] : s0[ni];
                floatx4 p;
#pragma unroll
                for (int j = 0; j < 4; ++j) p[j] = __builtin_amdgcn_exp2f(sv[j] - SHIFT2);
                if (st) lac1 += p; else lac0 += p;
#pragma unroll
                for (int j = 0; j < 4; ++j) {
                    int r = quad * 4 + j;
                    int chunk = ((ni * 16 + l16) >> 3) ^ ((r >> 1) & 7);
                    Ps[wave][st][r * 64 + chunk * 8 + (l16 & 7)] = (bf16_t)p[j];
                }
            }
        }

        bf16x8 pf[2][2];
#pragma unroll
        for (int st = 0; st < 2; ++st)
#pragma unroll
            for (int k2 = 0; k2 < 2; ++k2) {
                int chunk = (k2 * 4 + quad) ^ ((l16 >> 1) & 7);
                pf[st][k2] = *(const bf16x8*)&Ps[wave][st][l16 * 64 + chunk * 8];
            }

#pragma unroll
        for (int k2 = 0; k2 < 2; ++k2)
#pragma unroll
            for (int ni = 0; ni < 8; ++ni) {
                int r = ni * 16 + l16;
                int c = (k2 * 4 + quad) ^ (l16 & 7) ^ (((l16 >> 3) & 1) << 2);
                bf16x8 vf = *(const bf16x8*)&VTs[r * 64 + c * 8];
                o0[ni] = mfma_bf16(pf[0][k2], vf, o0[ni]);
                o1[ni] = mfma_bf16(pf[1][k2], vf, o1[ni]);
            }
        __syncthreads();
    }

#pragma unroll
    for (int off = 1; off < 16; off <<= 1) {
#pragma unroll
        for (int j = 0; j < 4; ++j) {
            lac0[j] += __shfl_xor(lac0[j], off);
            lac1[j] += __shfl_xor(lac1[j], off);
        }
    }

#pragma unroll
    for (int st = 0; st < 2; ++st) {
#pragma unroll
        for (int j = 0; j < 4; ++j) {
            float rl = 1.0f / (st ? lac1[j] : lac0[j]);
            int s_row = q0 + st * 16 + quad * 4 + j;
#pragma unroll
            for (int ni = 0; ni < 8; ++ni) {
                float v = (st ? o1[ni][j] : o0[ni][j]) * rl;
                int col = h * HD + ni * 16 + l16;
                ao[(long)s_row * DIM + col] = (bf16_t)v;
                if (s_row >= SIMG) out_txt[(long)(s_row - SIMG) * DIM + col] = v;
            }
        }
    }
}

// ---------------- launch ----------------
extern "C" void kernel_launch(void* const* d_in, const int* in_sizes, int n_in,
                              void* d_out, int out_size, void* d_ws, size_t ws_size,
                              hipStream_t stream) {
    const float* hid = (const float*)d_in[0];
    const float* enc = (const float*)d_in[1];
    const float* rope_cos = (const float*)d_in[2];
    const float* rope_sin = (const float*)d_in[3];
    const float* wq = (const float*)d_in[4];
    const float* bq = (const float*)d_in[5];
    const float* wk = (const float*)d_in[6];
    const float* bk = (const float*)d_in[7];
    const float* wv = (const float*)d_in[8];
    const float* bv = (const float*)d_in[9];
    const float* nqw = (const float*)d_in[10];
    const float* nkw = (const float*)d_in[11];
    const float* wo = (const float*)d_in[12];
    const float* bo = (const float*)d_in[13];
    float* out = (float*)d_out;

    char* ws = (char*)d_ws;
    bf16_t* xb   = (bf16_t*)(ws);                 // 2304*3072 bf16  = 14,155,776 B
    bf16_t* wTq  = (bf16_t*)(ws + 14155776L);     // 3*3072*3072 bf16
    bf16_t* woT  = (bf16_t*)(ws + 70778880L);     // 3072*3072 bf16
    bf16_t* qb   = (bf16_t*)(ws + 89653248L);     // 24*2304*128 bf16
    bf16_t* kbuf = (bf16_t*)(ws + 103809024L);
    bf16_t* vT   = (bf16_t*)(ws + 117964800L);
    bf16_t* ao   = (bf16_t*)(ws + 132120576L);    // 2304*3072 bf16

    k_convert_x<<<6912, 256, 0, stream>>>(hid, enc, xb);
    k_wT4<<<dim3(48, 48, 4), 256, 0, stream>>>(wq, wk, wv, wo, wTq, woT);
    k_gemm_qkv<<<dim3(72, 9), 512, 0, stream>>>(xb, wTq, bq, bk, bv, rope_cos, rope_sin,
                                                nqw, nkw, qb, kbuf, vT);
    k_attn<<<dim3(18, 24), 256, 0, stream>>>(qb, kbuf, vT, ao, out + (long)SIMG * DIM);
    k_gemm_bt<<<dim3(24, 8), 512, 0, stream>>>(ao, woT, bo, (bf16_t*)nullptr, out, SIMG, DIM, DIM);
}